// Round 19
// baseline (194.306 us; speedup 1.0000x reference)
//
#include <hip/hip_runtime.h>
#include <hip/hip_fp16.h>

#define IN_DIM 256
#define OUT_DIM 128
#define SLOPE 0.1f
#define EPB 4096          // edges per pass0/pass1 block
#define BSH 8             // bucket shift: 256 nodes per bucket

typedef __attribute__((ext_vector_type(8))) short short8;
typedef __attribute__((ext_vector_type(4))) float f32x4;

// round-to-nearest-even f32 -> bf16 bits
__device__ __forceinline__ unsigned bf16_rne(float f) {
    unsigned u = __float_as_uint(f);
    return (u + 0x7FFFu + ((u >> 16) & 1u)) >> 16;
}

// ---------------------------------------------------------------------------
// K0: blocks [0,128) pre-split W into bf16 hi/lo; blocks [128,..) = pass0:
// exact bucket histogram (bucket = src>>BSH) via LDS hist + NON-returning
// global adds.
// ---------------------------------------------------------------------------
__global__ __launch_bounds__(256) void wsplit_pass0_kernel(
    const float* __restrict__ W, short* __restrict__ Whi, short* __restrict__ Wlo,
    const int* __restrict__ edges, int* __restrict__ bucket_cnt, int E, int K)
{
    __shared__ int hist[4096];
    const int tid = threadIdx.x;
    if ((int)blockIdx.x < 128) {
        const int i = blockIdx.x * 256 + tid;   // 32768 W elements
        const float v = W[i];
        const unsigned hb = bf16_rne(v);
        const float hf = __uint_as_float(hb << 16);
        Whi[i] = (short)hb;
        Wlo[i] = (short)bf16_rne(v - hf);
        return;
    }
    const int pb = (int)blockIdx.x - 128;
    for (int t = tid; t < K; t += 256) hist[t] = 0;
    __syncthreads();
    const int e0 = pb * EPB;
    #pragma unroll
    for (int i = 0; i < EPB / 256; ++i) {
        const int e = e0 + i * 256 + tid;
        if (e < E) {
            const int src = ((const int2*)edges)[e].x;
            atomicAdd(&hist[src >> BSH], 1);
        }
    }
    __syncthreads();
    for (int t = tid; t < K; t += 256)
        if (hist[t]) atomicAdd(&bucket_cnt[t], hist[t]);   // non-returning
}

// ---------------------------------------------------------------------------
// K_scan: block 0 = exclusive scan of bucket_cnt (K<=4096) -> bucket_base,
// gcursor init, off[N]=E. All blocks: bidx==arange identity detection.
// ---------------------------------------------------------------------------
__global__ __launch_bounds__(256) void scan_ident_kernel(
    const int* __restrict__ bucket_cnt, int* __restrict__ bucket_base,
    int* __restrict__ gcursor, int* __restrict__ off,
    const int* __restrict__ bidx, int* __restrict__ flag, int N, int E, int K)
{
    const int tid = threadIdx.x;
    if (blockIdx.x == 0) {
        __shared__ int sc[4098];
        for (int t = tid; t < K; t += 256) sc[t] = bucket_cnt[t];
        __syncthreads();
        if (tid == 0) {
            int run = 0;
            for (int b = 0; b < K; ++b) { const int c = sc[b]; sc[b] = run; run += c; }
            sc[K] = run;
        }
        __syncthreads();
        for (int t = tid; t <= K; t += 256) {
            bucket_base[t] = sc[t];
            if (t < K) gcursor[t] = sc[t];
        }
        if (tid == 0) off[N] = E;
    }
    const int i = blockIdx.x * 256 + tid;
    if (i < N && bidx[i] != i) atomicOr(flag, 1);
}

// ---------------------------------------------------------------------------
// Fused K1: blocks [0, nP1) = pass1 (bucket scatter); blocks [nP1, ...) =
// gemm (R17 form — best measured: A-panel register preload in STAGING
// layout + XOR-swizzled A LDS slab; R18's fragment-layout preload reverted,
// it was neutral-to-negative).
// ---------------------------------------------------------------------------
__global__ __launch_bounds__(256) void gemm_pass1_kernel(
    const float* __restrict__ x, const short* __restrict__ Whi_g,
    const short* __restrict__ Wlo_g, const float* __restrict__ bias,
    const float* __restrict__ a, __half* __restrict__ emb_h,
    float* __restrict__ s1, float* __restrict__ s2,
    const int* __restrict__ edges, int* __restrict__ gcursor,
    int2* __restrict__ tmp, int N, int E, int K, int nP1)
{
    __shared__ short lds[12288];          // 24 KB (overlaid by both paths)

    const int tid = threadIdx.x;

    if ((int)blockIdx.x < nP1) {
        // ---------------- pass1: bucket scatter ----------------
        int* hist  = (int*)lds;           // K
        int* baseL = hist + K;            // K
        int* curL  = baseL + K;           // K
        for (int t = tid; t < K; t += 256) { hist[t] = 0; curL[t] = 0; }
        __syncthreads();
        const int e0 = (int)blockIdx.x * EPB;
        #pragma unroll
        for (int i = 0; i < EPB / 256; ++i) {
            const int e = e0 + i * 256 + tid;
            if (e < E) {
                const int src = ((const int2*)edges)[e].x;
                atomicAdd(&hist[src >> BSH], 1);
            }
        }
        __syncthreads();
        for (int t = tid; t < K; t += 256)
            if (hist[t]) baseL[t] = atomicAdd(&gcursor[t], hist[t]);  // returning
        __syncthreads();
        #pragma unroll
        for (int i = 0; i < EPB / 256; ++i) {
            const int e = e0 + i * 256 + tid;
            if (e < E) {
                const int2 ed = ((const int2*)edges)[e];
                const int b = ed.x >> BSH;
                const int s = atomicAdd(&curL[b], 1);                 // LDS, fast
                tmp[baseL[b] + s] = ed;
            }
        }
        return;
    }

    // ---------------- gemm path ----------------
    short* Ahi = lds;                     // [kc][arow^kc] 16B cells, 64x32 bf16
    short* Alo = lds + 2048;
    short* Bhi = lds + 4096;              // 128 x 32 bf16
    short* Blo = lds + 8192;

    const int l   = tid & 63;
    const int w   = tid >> 6;
    const int gm0 = ((int)blockIdx.x - nP1) * 64;

    // A staging: 64 rows x 4 chunks -> 1 chunk/thread
    const int arow = tid >> 2;            // 0..63
    const int akc  = tid & 3;             // 0..3
    const int gmA  = gm0 + arow;
    const bool av_ok = (gmA < N);
    // B staging: 128 rows x 4 chunks -> 2 chunks/thread
    const int brow = tid >> 1;            // 0..127
    const int bkc0 = (tid & 1) * 2;

    // ---- preload + convert the ENTIRE A-panel for this thread ----
    short8 xh[8], xl[8];
    #pragma unroll
    for (int ks = 0; ks < 8; ++ks) {
        float v[8];
        if (av_ok) {
            const float4 p0 = *(const float4*)&x[(size_t)gmA * IN_DIM + ks * 32 + akc * 8];
            const float4 p1 = *(const float4*)&x[(size_t)gmA * IN_DIM + ks * 32 + akc * 8 + 4];
            v[0]=p0.x; v[1]=p0.y; v[2]=p0.z; v[3]=p0.w;
            v[4]=p1.x; v[5]=p1.y; v[6]=p1.z; v[7]=p1.w;
        } else {
            #pragma unroll
            for (int j = 0; j < 8; ++j) v[j] = 0.f;
        }
        short8 h8, l8;
        #pragma unroll
        for (int j = 0; j < 8; ++j) {
            unsigned hb = bf16_rne(v[j]);
            float hf = __uint_as_float(hb << 16);
            h8[j] = (short)hb;
            l8[j] = (short)bf16_rne(v[j] - hf);
        }
        xh[ks] = h8;
        xl[ks] = l8;
    }
    const int awoff = akc * 512 + ((arow ^ akc) * 8);   // swizzled A write cell

    f32x4 acc[8];
    #pragma unroll
    for (int j = 0; j < 8; ++j) acc[j] = (f32x4)0.f;

    float bias_v[8], av1[8], av2[8];
    #pragma unroll
    for (int nf = 0; nf < 8; ++nf) {
        const int col = nf * 16 + (l & 15);
        bias_v[nf] = bias[col];
        av1[nf]    = a[col];
        av2[nf]    = a[OUT_DIM + col];
    }

    #pragma unroll
    for (int ks = 0; ks < 8; ++ks) {
        const int k0 = ks * 32;
        // ---- stage A: pure register -> LDS (swizzled) ----
        *(short8*)&Ahi[awoff] = xh[ks];
        *(short8*)&Alo[awoff] = xl[ks];
        // ---- stage B (pure copy of pre-split W, L2-resident) ----
        #pragma unroll
        for (int q = 0; q < 2; ++q) {
            const int kc = bkc0 + q;
            const short8 h8 = *(const short8*)&Whi_g[brow * IN_DIM + k0 + kc * 8];
            const short8 l8 = *(const short8*)&Wlo_g[brow * IN_DIM + k0 + kc * 8];
            *(short8*)&Bhi[kc * 1024 + brow * 8] = h8;
            *(short8*)&Blo[kc * 1024 + brow * 8] = l8;
        }
        __syncthreads();

        // ---- compute: wave w owns rows w*16..w*16+15, all 128 cols ----
        const int kcr    = l >> 4;
        const int arow_f = w * 16 + (l & 15);
        const int aoff   = kcr * 512 + ((arow_f ^ kcr) * 8);   // swizzled A read
        const short8 ah = *(const short8*)&Ahi[aoff];
        const short8 al = *(const short8*)&Alo[aoff];
        #pragma unroll
        for (int nf = 0; nf < 8; ++nf) {
            const int col = nf * 16 + (l & 15);
            const int boff = kcr * 1024 + col * 8;
            const short8 bh = *(const short8*)&Bhi[boff];
            const short8 bl = *(const short8*)&Blo[boff];
            acc[nf] = __builtin_amdgcn_mfma_f32_16x16x32_bf16(ah, bh, acc[nf], 0, 0, 0);
            acc[nf] = __builtin_amdgcn_mfma_f32_16x16x32_bf16(al, bh, acc[nf], 0, 0, 0);
            acc[nf] = __builtin_amdgcn_mfma_f32_16x16x32_bf16(ah, bl, acc[nf], 0, 0, 0);
        }
        __syncthreads();
    }

    // ---- fused epilogue: bias, s1/s2, emb -> fp16 via LDS repack ----
    __half* hl = (__half*)lds;   // [64][144]
    #pragma unroll
    for (int r = 0; r < 4; ++r) {
        const int lrow = w * 16 + (l >> 4) * 4 + r;
        float p1 = 0.f, p2 = 0.f;
        #pragma unroll
        for (int nf = 0; nf < 8; ++nf) {
            const float e = acc[nf][r] + bias_v[nf];
            p1 += e * av1[nf];
            p2 += e * av2[nf];
            hl[lrow * 144 + nf * 16 + (l & 15)] = __float2half(e);
        }
        p1 += __shfl_xor(p1, 1); p1 += __shfl_xor(p1, 2);
        p1 += __shfl_xor(p1, 4); p1 += __shfl_xor(p1, 8);
        p2 += __shfl_xor(p2, 1); p2 += __shfl_xor(p2, 2);
        p2 += __shfl_xor(p2, 4); p2 += __shfl_xor(p2, 8);
        const int gm = gm0 + lrow;
        if ((l & 15) == 0 && gm < N) { s1[gm] = p1; s2[gm] = p2; }
    }
    __syncthreads();
    // coalesced copy LDS fp16 -> global (64 rows x 16 uint4 = 1024 uint4)
    #pragma unroll
    for (int i = 0; i < 4; ++i) {
        const int idx = i * 256 + tid;
        const int row = idx >> 4, seg = idx & 15;
        if (gm0 + row < N) {
            const uint4 u = *(const uint4*)&hl[row * 144 + seg * 8];
            ((uint4*)emb_h)[(size_t)(gm0 + row) * 16 + seg] = u;
        }
    }
}

// ---------------------------------------------------------------------------
// K_pass2: one block per bucket (256 nodes). NEW: also computes the edge
// score (s1[src] bucket-local/L1 + s2[dst] L2-resident + exp) and writes
// edata = (dst, score) int2 — removing the s2 gather AND the exp from agg's
// per-node critical path. Score math identical, just relocated.
// ---------------------------------------------------------------------------
__global__ __launch_bounds__(256) void pass2_kernel(
    const int2* __restrict__ tmp, const int* __restrict__ bucket_base,
    const float* __restrict__ s1, const float* __restrict__ s2,
    int* __restrict__ off, int2* __restrict__ edata, int N)
{
    __shared__ int cnt[256];
    __shared__ int cur[256];

    const int tid = threadIdx.x;
    const int b   = blockIdx.x;
    const int v0  = b << BSH;
    const int nloc = min(256, N - v0);
    const int s0 = bucket_base[b];
    const int cntE = bucket_base[b + 1] - s0;

    cnt[tid] = 0;
    __syncthreads();
    for (int e = tid; e < cntE; e += 256)
        atomicAdd(&cnt[tmp[s0 + e].x - v0], 1);
    __syncthreads();

    // exclusive scan of cnt[256]
    const int ts = cnt[tid];
    cur[tid] = ts;
    __syncthreads();
    for (int d = 1; d < 256; d <<= 1) {
        int xv = (tid >= d) ? cur[tid - d] : 0;
        __syncthreads();
        cur[tid] += xv;
        __syncthreads();
    }
    const int mypre = cur[tid] - ts;    // exclusive prefix
    __syncthreads();
    cur[tid] = mypre;
    if (tid < nloc) off[v0 + tid] = s0 + mypre;
    __syncthreads();

    // scatter (dst, score) into edata via LDS cursors
    for (int e = tid; e < cntE; e += 256) {
        const int2 ed = tmp[s0 + e];
        const float ll = s1[ed.x] + s2[ed.y];
        const float sc = __expf(ll > 0.f ? ll : SLOPE * ll);
        const int sl = atomicAdd(&cur[ed.x - v0], 1);
        edata[s0 + sl] = make_int2(ed.y, __float_as_int(sc));
    }
}

// ---------------------------------------------------------------------------
// K3: gather aggregation. Wave = 1 node, 4 groups x 16 col-lanes.
// NEW: edges carry precomputed (dst,score) — each group loads its edge's
// pair via same-address broadcast (no LDS staging, no wave barriers, no s2
// gather, no exp). Chain per batch: edata load -> row gather -> fma_mix.
// 8 independent row-gathers in flight per lane (32 edges/iter).
// ---------------------------------------------------------------------------
__global__ __launch_bounds__(256) void agg_kernel(
    const int* __restrict__ off, const int2* __restrict__ edata,
    const __half* __restrict__ emb_h, const int* __restrict__ flag,
    float* __restrict__ results, float* __restrict__ out, int N)
{
    const int wid  = (int)((blockIdx.x * 256u + threadIdx.x) >> 6);
    const int lane = threadIdx.x & 63;
    if (wid >= N) return;
    const int eg = lane >> 4;
    const int cl = lane & 15;
    const int beg = off[wid];
    const int end = off[wid + 1];

    const float4* __restrict__ embrow = (const float4*)emb_h;

    float av[8];
    #pragma unroll
    for (int k = 0; k < 8; ++k) av[k] = 0.f;
    float rs = 0.f;

    int base = beg;
    // ---- main loop: 32 edges/iter, unguarded ----
    for (; base + 32 <= end; base += 32) {
        int2 pq[8];
        #pragma unroll
        for (int q = 0; q < 8; ++q)
            pq[q] = edata[base + q * 4 + eg];          // group-broadcast load
        float4 vq[8];
        #pragma unroll
        for (int q = 0; q < 8; ++q)
            vq[q] = embrow[(size_t)pq[q].x * 16 + cl];
        #pragma unroll
        for (int q = 0; q < 8; ++q) {
            const float sc = __int_as_float(pq[q].y);
            rs += sc;
            const unsigned* up = reinterpret_cast<const unsigned*>(&vq[q]);
            #pragma unroll
            for (int p = 0; p < 4; ++p) {
                asm("v_fma_mix_f32 %0, %1, %2, %0 op_sel:[0,0,0] op_sel_hi:[1,0,0]"
                    : "+v"(av[2 * p]) : "v"(up[p]), "v"(sc));
                asm("v_fma_mix_f32 %0, %1, %2, %0 op_sel:[1,0,0] op_sel_hi:[1,0,0]"
                    : "+v"(av[2 * p + 1]) : "v"(up[p]), "v"(sc));
            }
        }
    }
    // ---- tail: only ceil(rem/4) phases run (wave-uniform skip) ----
    if (base < end) {
        const int nq = ((end - base) + 3) >> 2;        // 1..8
        int2 pq[8];
        #pragma unroll
        for (int q = 0; q < 8; ++q) {
            pq[q] = make_int2(0, 0);
            if (q < nq) {
                const int idx = base + q * 4 + eg;
                if (idx < end) pq[q] = edata[idx];
            }
        }
        float4 vq[8];
        #pragma unroll
        for (int q = 0; q < 8; ++q)
            if (q < nq) vq[q] = embrow[(size_t)pq[q].x * 16 + cl];
        #pragma unroll
        for (int q = 0; q < 8; ++q) {
            if (q < nq) {
                const float sc = __int_as_float(pq[q].y);
                rs += sc;
                const unsigned* up = reinterpret_cast<const unsigned*>(&vq[q]);
                #pragma unroll
                for (int p = 0; p < 4; ++p) {
                    asm("v_fma_mix_f32 %0, %1, %2, %0 op_sel:[0,0,0] op_sel_hi:[1,0,0]"
                        : "+v"(av[2 * p]) : "v"(up[p]), "v"(sc));
                    asm("v_fma_mix_f32 %0, %1, %2, %0 op_sel:[1,0,0] op_sel_hi:[1,0,0]"
                        : "+v"(av[2 * p + 1]) : "v"(up[p]), "v"(sc));
                }
            }
        }
    }

    // reduce across the 4 edge-groups (lane bits 4,5); rs is group-uniform
    #pragma unroll
    for (int k = 0; k < 8; ++k) {
        av[k] += __shfl_xor(av[k], 16);
        av[k] += __shfl_xor(av[k], 32);
    }
    rs += __shfl_xor(rs, 16);
    rs += __shfl_xor(rs, 32);

    const float inv = 1.f / (rs > 0.f ? rs : 1.f);
    if (eg == 0) {
        float* dbuf = (*flag == 0) ? out : results;
        float4* rp = (float4*)&dbuf[(size_t)wid * 128 + cl * 8];
        rp[0] = make_float4(av[0] * inv, av[1] * inv, av[2] * inv, av[3] * inv);
        rp[1] = make_float4(av[4] * inv, av[5] * inv, av[6] * inv, av[7] * inv);
    }
}

// ---------------------------------------------------------------------------
// K4: out[i] = results[batch_idx[i]] — skipped when identity (agg wrote out)
// ---------------------------------------------------------------------------
__global__ __launch_bounds__(256) void gather_kernel(
    const float* __restrict__ results, const int* __restrict__ bidx,
    const int* __restrict__ flag, float* __restrict__ out, int N)
{
    if (*flag == 0) return;
    const unsigned i = blockIdx.x * 256u + threadIdx.x;
    if (i >= (unsigned)N * 32u) return;
    const unsigned n = i >> 5, c = i & 31;
    ((float4*)out)[i] = ((const float4*)results)[(size_t)bidx[n] * 32 + c];
}

extern "C" void kernel_launch(void* const* d_in, const int* in_sizes, int n_in,
                              void* d_out, int out_size, void* d_ws, size_t ws_size,
                              hipStream_t stream) {
    const float* x     = (const float*)d_in[0];
    const float* W     = (const float*)d_in[1];
    const float* b     = (const float*)d_in[2];
    const float* a     = (const float*)d_in[3];
    const int*   edges = (const int*)d_in[4];
    const int*   bidx  = (const int*)d_in[5];

    const int N = in_sizes[5];
    const int E = in_sizes[4] / 2;
    const int K = (N + 255) >> BSH;          // buckets of 256 nodes

    // workspace
    float*  results = (float*)d_ws;                              // N*128 f
    __half* emb_h   = (__half*)(results + (size_t)N * OUT_DIM);  // N*128 h
    int2*   tmp     = (int2*)(emb_h + (size_t)N * OUT_DIM);      // E int2
    int2*   edata   = tmp + E;                                   // E int2
    float*  s1      = (float*)(edata + E);                       // N
    float*  s2      = s1 + N;                                    // N
    int*    off     = (int*)(s2 + N);                            // N+1
    int*    bucket_cnt  = off + N + 1;                           // K
    int*    flag        = bucket_cnt + K;                        // 1
    int*    bucket_base = flag + 1;                              // K+1
    int*    gcursor     = bucket_base + K + 1;                   // K
    short*  Whi     = (short*)(gcursor + K);
    short*  Wlo     = Whi + OUT_DIM * IN_DIM;

    // zero bucket_cnt[K] + flag together
    hipMemsetAsync(bucket_cnt, 0, (size_t)(K + 1) * sizeof(int), stream);

    const int nP = (E + EPB - 1) / EPB;      // pass0/pass1 blocks

    wsplit_pass0_kernel<<<128 + nP, 256, 0, stream>>>(
        W, Whi, Wlo, edges, bucket_cnt, E, K);

    const int nIdent = (N + 255) / 256;
    scan_ident_kernel<<<nIdent, 256, 0, stream>>>(
        bucket_cnt, bucket_base, gcursor, off, bidx, flag, N, E, K);

    const int nGemm = (N + 63) / 64;
    gemm_pass1_kernel<<<nP + nGemm, 256, 0, stream>>>(
        x, Whi, Wlo, b, a, emb_h, s1, s2, edges, gcursor, tmp, N, E, K, nP);

    pass2_kernel<<<K, 256, 0, stream>>>(tmp, bucket_base, s1, s2, off, edata, N);

    const unsigned aggThreads = (unsigned)N * 64u;
    agg_kernel<<<(aggThreads + 255u) / 256u, 256, 0, stream>>>(
        off, edata, emb_h, flag, results, (float*)d_out, N);

    const unsigned gatherThreads = (unsigned)N * 32u;
    gather_kernel<<<(gatherThreads + 255u) / 256u, 256, 0, stream>>>(
        results, bidx, flag, (float*)d_out, N);
}

// Round 20
// 185.092 us; speedup vs baseline: 1.0498x; 1.0498x over previous
//
#include <hip/hip_runtime.h>
#include <hip/hip_fp16.h>

#define IN_DIM 256
#define OUT_DIM 128
#define SLOPE 0.1f
#define EPB 4096          // edges per pass0/pass1 block
#define BSH 8             // bucket shift: 256 nodes per bucket

typedef __attribute__((ext_vector_type(8))) short short8;
typedef __attribute__((ext_vector_type(4))) float f32x4;

// round-to-nearest-even f32 -> bf16 bits
__device__ __forceinline__ unsigned bf16_rne(float f) {
    unsigned u = __float_as_uint(f);
    return (u + 0x7FFFu + ((u >> 16) & 1u)) >> 16;
}

// ---------------------------------------------------------------------------
// K0: blocks [0,128) pre-split W into bf16 hi/lo; blocks [128,..) = pass0:
// exact bucket histogram (bucket = src>>BSH) via LDS hist + NON-returning
// global adds.
// ---------------------------------------------------------------------------
__global__ __launch_bounds__(256) void wsplit_pass0_kernel(
    const float* __restrict__ W, short* __restrict__ Whi, short* __restrict__ Wlo,
    const int* __restrict__ edges, int* __restrict__ bucket_cnt, int E, int K)
{
    __shared__ int hist[4096];
    const int tid = threadIdx.x;
    if ((int)blockIdx.x < 128) {
        const int i = blockIdx.x * 256 + tid;   // 32768 W elements
        const float v = W[i];
        const unsigned hb = bf16_rne(v);
        const float hf = __uint_as_float(hb << 16);
        Whi[i] = (short)hb;
        Wlo[i] = (short)bf16_rne(v - hf);
        return;
    }
    const int pb = (int)blockIdx.x - 128;
    for (int t = tid; t < K; t += 256) hist[t] = 0;
    __syncthreads();
    const int e0 = pb * EPB;
    #pragma unroll
    for (int i = 0; i < EPB / 256; ++i) {
        const int e = e0 + i * 256 + tid;
        if (e < E) {
            const int src = ((const int2*)edges)[e].x;
            atomicAdd(&hist[src >> BSH], 1);
        }
    }
    __syncthreads();
    for (int t = tid; t < K; t += 256)
        if (hist[t]) atomicAdd(&bucket_cnt[t], hist[t]);   // non-returning
}

// ---------------------------------------------------------------------------
// K_scan: block 0 = exclusive scan of bucket_cnt (K<=4096) -> bucket_base,
// gcursor init, off[N]=E. All blocks: bidx==arange identity detection.
// ---------------------------------------------------------------------------
__global__ __launch_bounds__(256) void scan_ident_kernel(
    const int* __restrict__ bucket_cnt, int* __restrict__ bucket_base,
    int* __restrict__ gcursor, int* __restrict__ off,
    const int* __restrict__ bidx, int* __restrict__ flag, int N, int E, int K)
{
    const int tid = threadIdx.x;
    if (blockIdx.x == 0) {
        __shared__ int sc[4098];
        for (int t = tid; t < K; t += 256) sc[t] = bucket_cnt[t];
        __syncthreads();
        if (tid == 0) {
            int run = 0;
            for (int b = 0; b < K; ++b) { const int c = sc[b]; sc[b] = run; run += c; }
            sc[K] = run;
        }
        __syncthreads();
        for (int t = tid; t <= K; t += 256) {
            bucket_base[t] = sc[t];
            if (t < K) gcursor[t] = sc[t];
        }
        if (tid == 0) off[N] = E;
    }
    const int i = blockIdx.x * 256 + tid;
    if (i < N && bidx[i] != i) atomicOr(flag, 1);
}

// ---------------------------------------------------------------------------
// Fused K1: blocks [0, nP1) = pass1 (bucket scatter); blocks [nP1, ...) =
// gemm (best-measured R17 form): A-panel register preload in staging layout,
// XOR-swizzled A LDS slab (arow^akc), B staged per K-step from L2-resident
// pre-split W. (R18 fragment-layout preload and R19 score-precompute both
// regressed and are reverted.)
// ---------------------------------------------------------------------------
__global__ __launch_bounds__(256) void gemm_pass1_kernel(
    const float* __restrict__ x, const short* __restrict__ Whi_g,
    const short* __restrict__ Wlo_g, const float* __restrict__ bias,
    const float* __restrict__ a, __half* __restrict__ emb_h,
    float* __restrict__ s1, float* __restrict__ s2,
    const int* __restrict__ edges, int* __restrict__ gcursor,
    int2* __restrict__ tmp, int N, int E, int K, int nP1)
{
    __shared__ short lds[12288];          // 24 KB (overlaid by both paths)

    const int tid = threadIdx.x;

    if ((int)blockIdx.x < nP1) {
        // ---------------- pass1: bucket scatter ----------------
        int* hist  = (int*)lds;           // K
        int* baseL = hist + K;            // K
        int* curL  = baseL + K;           // K
        for (int t = tid; t < K; t += 256) { hist[t] = 0; curL[t] = 0; }
        __syncthreads();
        const int e0 = (int)blockIdx.x * EPB;
        #pragma unroll
        for (int i = 0; i < EPB / 256; ++i) {
            const int e = e0 + i * 256 + tid;
            if (e < E) {
                const int src = ((const int2*)edges)[e].x;
                atomicAdd(&hist[src >> BSH], 1);
            }
        }
        __syncthreads();
        for (int t = tid; t < K; t += 256)
            if (hist[t]) baseL[t] = atomicAdd(&gcursor[t], hist[t]);  // returning
        __syncthreads();
        #pragma unroll
        for (int i = 0; i < EPB / 256; ++i) {
            const int e = e0 + i * 256 + tid;
            if (e < E) {
                const int2 ed = ((const int2*)edges)[e];
                const int b = ed.x >> BSH;
                const int s = atomicAdd(&curL[b], 1);                 // LDS, fast
                tmp[baseL[b] + s] = ed;
            }
        }
        return;
    }

    // ---------------- gemm path ----------------
    short* Ahi = lds;                     // [kc][arow^kc] 16B cells, 64x32 bf16
    short* Alo = lds + 2048;
    short* Bhi = lds + 4096;              // 128 x 32 bf16
    short* Blo = lds + 8192;

    const int l   = tid & 63;
    const int w   = tid >> 6;
    const int gm0 = ((int)blockIdx.x - nP1) * 64;

    // A staging: 64 rows x 4 chunks -> 1 chunk/thread
    const int arow = tid >> 2;            // 0..63
    const int akc  = tid & 3;             // 0..3
    const int gmA  = gm0 + arow;
    const bool av_ok = (gmA < N);
    // B staging: 128 rows x 4 chunks -> 2 chunks/thread
    const int brow = tid >> 1;            // 0..127
    const int bkc0 = (tid & 1) * 2;

    // ---- preload + convert the ENTIRE A-panel for this thread ----
    short8 xh[8], xl[8];
    #pragma unroll
    for (int ks = 0; ks < 8; ++ks) {
        float v[8];
        if (av_ok) {
            const float4 p0 = *(const float4*)&x[(size_t)gmA * IN_DIM + ks * 32 + akc * 8];
            const float4 p1 = *(const float4*)&x[(size_t)gmA * IN_DIM + ks * 32 + akc * 8 + 4];
            v[0]=p0.x; v[1]=p0.y; v[2]=p0.z; v[3]=p0.w;
            v[4]=p1.x; v[5]=p1.y; v[6]=p1.z; v[7]=p1.w;
        } else {
            #pragma unroll
            for (int j = 0; j < 8; ++j) v[j] = 0.f;
        }
        short8 h8, l8;
        #pragma unroll
        for (int j = 0; j < 8; ++j) {
            unsigned hb = bf16_rne(v[j]);
            float hf = __uint_as_float(hb << 16);
            h8[j] = (short)hb;
            l8[j] = (short)bf16_rne(v[j] - hf);
        }
        xh[ks] = h8;
        xl[ks] = l8;
    }
    const int awoff = akc * 512 + ((arow ^ akc) * 8);   // swizzled A write cell

    f32x4 acc[8];
    #pragma unroll
    for (int j = 0; j < 8; ++j) acc[j] = (f32x4)0.f;

    float bias_v[8], av1[8], av2[8];
    #pragma unroll
    for (int nf = 0; nf < 8; ++nf) {
        const int col = nf * 16 + (l & 15);
        bias_v[nf] = bias[col];
        av1[nf]    = a[col];
        av2[nf]    = a[OUT_DIM + col];
    }

    #pragma unroll
    for (int ks = 0; ks < 8; ++ks) {
        const int k0 = ks * 32;
        // ---- stage A: pure register -> LDS (swizzled) ----
        *(short8*)&Ahi[awoff] = xh[ks];
        *(short8*)&Alo[awoff] = xl[ks];
        // ---- stage B (pure copy of pre-split W, L2-resident) ----
        #pragma unroll
        for (int q = 0; q < 2; ++q) {
            const int kc = bkc0 + q;
            const short8 h8 = *(const short8*)&Whi_g[brow * IN_DIM + k0 + kc * 8];
            const short8 l8 = *(const short8*)&Wlo_g[brow * IN_DIM + k0 + kc * 8];
            *(short8*)&Bhi[kc * 1024 + brow * 8] = h8;
            *(short8*)&Blo[kc * 1024 + brow * 8] = l8;
        }
        __syncthreads();

        // ---- compute: wave w owns rows w*16..w*16+15, all 128 cols ----
        const int kcr    = l >> 4;
        const int arow_f = w * 16 + (l & 15);
        const int aoff   = kcr * 512 + ((arow_f ^ kcr) * 8);   // swizzled A read
        const short8 ah = *(const short8*)&Ahi[aoff];
        const short8 al = *(const short8*)&Alo[aoff];
        #pragma unroll
        for (int nf = 0; nf < 8; ++nf) {
            const int col = nf * 16 + (l & 15);
            const int boff = kcr * 1024 + col * 8;
            const short8 bh = *(const short8*)&Bhi[boff];
            const short8 bl = *(const short8*)&Blo[boff];
            acc[nf] = __builtin_amdgcn_mfma_f32_16x16x32_bf16(ah, bh, acc[nf], 0, 0, 0);
            acc[nf] = __builtin_amdgcn_mfma_f32_16x16x32_bf16(al, bh, acc[nf], 0, 0, 0);
            acc[nf] = __builtin_amdgcn_mfma_f32_16x16x32_bf16(ah, bl, acc[nf], 0, 0, 0);
        }
        __syncthreads();
    }

    // ---- fused epilogue: bias, s1/s2, emb -> fp16 via LDS repack ----
    __half* hl = (__half*)lds;   // [64][144]
    #pragma unroll
    for (int r = 0; r < 4; ++r) {
        const int lrow = w * 16 + (l >> 4) * 4 + r;
        float p1 = 0.f, p2 = 0.f;
        #pragma unroll
        for (int nf = 0; nf < 8; ++nf) {
            const float e = acc[nf][r] + bias_v[nf];
            p1 += e * av1[nf];
            p2 += e * av2[nf];
            hl[lrow * 144 + nf * 16 + (l & 15)] = __float2half(e);
        }
        p1 += __shfl_xor(p1, 1); p1 += __shfl_xor(p1, 2);
        p1 += __shfl_xor(p1, 4); p1 += __shfl_xor(p1, 8);
        p2 += __shfl_xor(p2, 1); p2 += __shfl_xor(p2, 2);
        p2 += __shfl_xor(p2, 4); p2 += __shfl_xor(p2, 8);
        const int gm = gm0 + lrow;
        if ((l & 15) == 0 && gm < N) { s1[gm] = p1; s2[gm] = p2; }
    }
    __syncthreads();
    // coalesced copy LDS fp16 -> global (64 rows x 16 uint4 = 1024 uint4)
    #pragma unroll
    for (int i = 0; i < 4; ++i) {
        const int idx = i * 256 + tid;
        const int row = idx >> 4, seg = idx & 15;
        if (gm0 + row < N) {
            const uint4 u = *(const uint4*)&hl[row * 144 + seg * 8];
            ((uint4*)emb_h)[(size_t)(gm0 + row) * 16 + seg] = u;
        }
    }
}

// ---------------------------------------------------------------------------
// K_pass2: one block per bucket (256 nodes, K=391 blocks). LDS per-node
// counters -> block scan -> off[] + csr written directly. LDS atomics only.
// ---------------------------------------------------------------------------
__global__ __launch_bounds__(256) void pass2_kernel(
    const int2* __restrict__ tmp, const int* __restrict__ bucket_base,
    int* __restrict__ off, int* __restrict__ csr, int N)
{
    __shared__ int cnt[256];
    __shared__ int cur[256];

    const int tid = threadIdx.x;
    const int b   = blockIdx.x;
    const int v0  = b << BSH;
    const int nloc = min(256, N - v0);
    const int s0 = bucket_base[b];
    const int cntE = bucket_base[b + 1] - s0;

    cnt[tid] = 0;
    __syncthreads();
    for (int e = tid; e < cntE; e += 256)
        atomicAdd(&cnt[tmp[s0 + e].x - v0], 1);
    __syncthreads();

    // exclusive scan of cnt[256]
    const int ts = cnt[tid];
    cur[tid] = ts;
    __syncthreads();
    for (int d = 1; d < 256; d <<= 1) {
        int xv = (tid >= d) ? cur[tid - d] : 0;
        __syncthreads();
        cur[tid] += xv;
        __syncthreads();
    }
    const int mypre = cur[tid] - ts;    // exclusive prefix
    __syncthreads();
    cur[tid] = mypre;
    if (tid < nloc) off[v0 + tid] = s0 + mypre;
    __syncthreads();

    // scatter dst into csr via LDS cursors
    for (int e = tid; e < cntE; e += 256) {
        const int2 ed = tmp[s0 + e];
        const int sl = atomicAdd(&cur[ed.x - v0], 1);
        csr[s0 + sl] = ed.y;
    }
}

// ---------------------------------------------------------------------------
// K3: gather aggregation. Wave = 1 node.
// Phase 1 (lane-parallel, per 64-edge tile): each lane scores ONE edge and
// stashes (dst,score) in wave-private LDS; row-sum accumulates here.
// Phase 2: 4 groups x 16 col-lanes read pairs back via broadcast ds_read,
// 32 edges per iter; inner accumulate via v_fma_mix_f32.
// ---------------------------------------------------------------------------
__global__ __launch_bounds__(256) void agg_kernel(
    const int* __restrict__ off, const int* __restrict__ csr,
    const float* __restrict__ s1, const float* __restrict__ s2,
    const __half* __restrict__ emb_h, const int* __restrict__ flag,
    float* __restrict__ results, float* __restrict__ out, int N)
{
    __shared__ int2 sl[4][64];   // [wave][slot] = {dst, score bits}

    const int wid  = (int)((blockIdx.x * 256u + threadIdx.x) >> 6);
    const int lane = threadIdx.x & 63;
    const int wv   = threadIdx.x >> 6;
    if (wid >= N) return;
    const int eg = lane >> 4;
    const int cl = lane & 15;
    const int beg = off[wid];
    const int end = off[wid + 1];
    const float s1n = s1[wid];

    const float4* __restrict__ embrow = (const float4*)emb_h;
    int2* slot = &sl[wv][0];

    float av[8];
    #pragma unroll
    for (int k = 0; k < 8; ++k) av[k] = 0.f;
    float rsl = 0.f;

    for (int tile = beg; tile < end; tile += 64) {
        const int cnt = min(64, end - tile);           // wave-uniform
        int d = 0; float sc = 0.f;
        if (lane < cnt) {
            d = csr[tile + lane];
            const float ll = s1n + s2[d];
            sc = __expf(ll > 0.f ? ll : SLOPE * ll);
        }
        rsl += sc;
        slot[lane] = make_int2(d, __float_as_int(sc));
        __builtin_amdgcn_wave_barrier();
        for (int j0 = 0; j0 < cnt; j0 += 32) {
            const int nq = ((cnt - j0) + 3) >> 2;      // 1..8, wave-uniform
            int dq[8]; float scq[8];
            #pragma unroll
            for (int q = 0; q < 8; ++q) {
                dq[q] = 0; scq[q] = 0.f;
                if (q < nq) {
                    const int2 p = slot[j0 + q * 4 + eg];
                    dq[q] = p.x; scq[q] = __int_as_float(p.y);
                }
            }
            float4 vq[8];
            #pragma unroll
            for (int q = 0; q < 8; ++q)
                if (q < nq) vq[q] = embrow[(size_t)dq[q] * 16 + cl];
            #pragma unroll
            for (int q = 0; q < 8; ++q) {
                if (q < nq) {
                    const unsigned* up = reinterpret_cast<const unsigned*>(&vq[q]);
                    #pragma unroll
                    for (int p = 0; p < 4; ++p) {
                        asm("v_fma_mix_f32 %0, %1, %2, %0 op_sel:[0,0,0] op_sel_hi:[1,0,0]"
                            : "+v"(av[2 * p]) : "v"(up[p]), "v"(scq[q]));
                        asm("v_fma_mix_f32 %0, %1, %2, %0 op_sel:[1,0,0] op_sel_hi:[1,0,0]"
                            : "+v"(av[2 * p + 1]) : "v"(up[p]), "v"(scq[q]));
                    }
                }
            }
        }
        __builtin_amdgcn_wave_barrier();
    }

    float rs = rsl;
    rs += __shfl_xor(rs, 1);  rs += __shfl_xor(rs, 2);
    rs += __shfl_xor(rs, 4);  rs += __shfl_xor(rs, 8);
    rs += __shfl_xor(rs, 16); rs += __shfl_xor(rs, 32);
    #pragma unroll
    for (int k = 0; k < 8; ++k) {
        av[k] += __shfl_xor(av[k], 16);
        av[k] += __shfl_xor(av[k], 32);
    }

    const float inv = 1.f / (rs > 0.f ? rs : 1.f);
    if (eg == 0) {
        float* dbuf = (*flag == 0) ? out : results;
        float4* rp = (float4*)&dbuf[(size_t)wid * 128 + cl * 8];
        rp[0] = make_float4(av[0] * inv, av[1] * inv, av[2] * inv, av[3] * inv);
        rp[1] = make_float4(av[4] * inv, av[5] * inv, av[6] * inv, av[7] * inv);
    }
}

// ---------------------------------------------------------------------------
// K4: out[i] = results[batch_idx[i]] — skipped when identity (agg wrote out)
// ---------------------------------------------------------------------------
__global__ __launch_bounds__(256) void gather_kernel(
    const float* __restrict__ results, const int* __restrict__ bidx,
    const int* __restrict__ flag, float* __restrict__ out, int N)
{
    if (*flag == 0) return;
    const unsigned i = blockIdx.x * 256u + threadIdx.x;
    if (i >= (unsigned)N * 32u) return;
    const unsigned n = i >> 5, c = i & 31;
    ((float4*)out)[i] = ((const float4*)results)[(size_t)bidx[n] * 32 + c];
}

extern "C" void kernel_launch(void* const* d_in, const int* in_sizes, int n_in,
                              void* d_out, int out_size, void* d_ws, size_t ws_size,
                              hipStream_t stream) {
    const float* x     = (const float*)d_in[0];
    const float* W     = (const float*)d_in[1];
    const float* b     = (const float*)d_in[2];
    const float* a     = (const float*)d_in[3];
    const int*   edges = (const int*)d_in[4];
    const int*   bidx  = (const int*)d_in[5];

    const int N = in_sizes[5];
    const int E = in_sizes[4] / 2;
    const int K = (N + 255) >> BSH;          // buckets of 256 nodes

    // workspace
    float*  results = (float*)d_ws;                              // N*128 f
    __half* emb_h   = (__half*)(results + (size_t)N * OUT_DIM);  // N*128 h
    int2*   tmp     = (int2*)(emb_h + (size_t)N * OUT_DIM);      // E int2
    int*    csr     = (int*)(tmp + E);                           // E
    float*  s1      = (float*)(csr + E);                         // N
    float*  s2      = s1 + N;                                    // N
    int*    off     = (int*)(s2 + N);                            // N+1
    int*    bucket_cnt  = off + N + 1;                           // K
    int*    flag        = bucket_cnt + K;                        // 1
    int*    bucket_base = flag + 1;                              // K+1
    int*    gcursor     = bucket_base + K + 1;                   // K
    short*  Whi     = (short*)(gcursor + K);
    short*  Wlo     = Whi + OUT_DIM * IN_DIM;

    // zero bucket_cnt[K] + flag together
    hipMemsetAsync(bucket_cnt, 0, (size_t)(K + 1) * sizeof(int), stream);

    const int nP = (E + EPB - 1) / EPB;      // pass0/pass1 blocks

    wsplit_pass0_kernel<<<128 + nP, 256, 0, stream>>>(
        W, Whi, Wlo, edges, bucket_cnt, E, K);

    const int nIdent = (N + 255) / 256;
    scan_ident_kernel<<<nIdent, 256, 0, stream>>>(
        bucket_cnt, bucket_base, gcursor, off, bidx, flag, N, E, K);

    const int nGemm = (N + 63) / 64;
    gemm_pass1_kernel<<<nP + nGemm, 256, 0, stream>>>(
        x, Whi, Wlo, b, a, emb_h, s1, s2, edges, gcursor, tmp, N, E, K, nP);

    pass2_kernel<<<K, 256, 0, stream>>>(tmp, bucket_base, off, csr, N);

    const unsigned aggThreads = (unsigned)N * 64u;
    agg_kernel<<<(aggThreads + 255u) / 256u, 256, 0, stream>>>(
        off, csr, s1, s2, emb_h, flag, results, (float*)d_out, N);

    const unsigned gatherThreads = (unsigned)N * 32u;
    gather_kernel<<<(gatherThreads + 255u) / 256u, 256, 0, stream>>>(
        results, bidx, flag, (float*)d_out, N);
}